// Round 15
// baseline (749.010 us; speedup 1.0000x reference)
//
#include <hip/hip_runtime.h>

typedef unsigned short u16;
typedef __attribute__((ext_vector_type(8))) short bf16x8;   // MFMA A/B operand (8 bf16 = 4 VGPR)
typedef __attribute__((ext_vector_type(8))) unsigned short u16x8;
typedef __attribute__((ext_vector_type(4))) float f32x4;    // MFMA C/D operand

#define HIDDEN 4096
#define NH 32
#define NKV 8
#define HD 128
#define BB 2
#define SS 2048
#define TOK (BB * SS)   // 4096
#define MAXPOS 4096
#define NQKV 6144        // 4096 + 1024 + 1024

__device__ __forceinline__ u16 f2bf(float f) {
  unsigned u = __float_as_uint(f);
  u += 0x7FFFu + ((u >> 16) & 1u);   // RNE
  return (u16)(u >> 16);
}
__device__ __forceinline__ float bf2f(u16 u) {
  return __uint_as_float(((unsigned)u) << 16);
}

__device__ __forceinline__ void gload_lds16(const u16* g, u16* l) {
  __builtin_amdgcn_global_load_lds(
      (const __attribute__((address_space(1))) unsigned int*)g,
      (__attribute__((address_space(3))) unsigned int*)l, 16, 0, 0);
}

// XOR-swizzled LDS addressing (T2): same involution on write and read.
__device__ __forceinline__ u16* swzp(u16* base, int row, int col, int stride) {
  int off = (row * stride + col) * 2;
  off ^= (row & 7) << 4;
  return (u16*)((char*)base + off);
}
__device__ __forceinline__ const u16* swzc(const u16* base, int row, int col, int stride) {
  int off = (row * stride + col) * 2;
  off ^= (row & 7) << 4;
  return (const u16*)((const char*)base + off);
}

// ---------------- conversion kernels ----------------

__global__ void conv_bf16(const float* __restrict__ X, u16* __restrict__ Y, int n8) {
  int i = blockIdx.x * 256 + threadIdx.x;
  if (i >= n8) return;
  const float4* p = (const float4*)X;
  float4 a = p[2 * (long)i], b = p[2 * (long)i + 1];
  u16x8 o;
  o[0] = f2bf(a.x); o[1] = f2bf(a.y); o[2] = f2bf(a.z); o[3] = f2bf(a.w);
  o[4] = f2bf(b.x); o[5] = f2bf(b.y); o[6] = f2bf(b.z); o[7] = f2bf(b.w);
  *(u16x8*)&Y[(long)i * 8] = o;
}

// W [K][N] fp32  ->  Wt [N][K] bf16
__global__ __launch_bounds__(256) void conv_transpose(const float* __restrict__ W,
                                                      u16* __restrict__ Wt,
                                                      int K, int N) {
  __shared__ float tile[64][65];
  const int n0 = blockIdx.x * 64, k0 = blockIdx.y * 64;
  const int t = threadIdx.x;
  const int r = t >> 4, c4 = (t & 15) * 4;
#pragma unroll
  for (int i = 0; i < 4; i++) {
    float4 v = *(const float4*)&W[(long)(k0 + r + i * 16) * N + n0 + c4];
    tile[r + i * 16][c4 + 0] = v.x;
    tile[r + i * 16][c4 + 1] = v.y;
    tile[r + i * 16][c4 + 2] = v.z;
    tile[r + i * 16][c4 + 3] = v.w;
  }
  __syncthreads();
#pragma unroll
  for (int i = 0; i < 4; i++) {
    int n = r + i * 16;
    ushort4 o;
    o.x = f2bf(tile[c4 + 0][n]);
    o.y = f2bf(tile[c4 + 1][n]);
    o.z = f2bf(tile[c4 + 2][n]);
    o.w = f2bf(tile[c4 + 3][n]);
    *(ushort4*)&Wt[(long)(n0 + n) * K + k0 + c4] = o;
  }
}

// ---------------- RoPE ----------------

__global__ void rope_table(float* __restrict__ st, float* __restrict__ ct) {
  int i = blockIdx.x * 256 + threadIdx.x;   // MAXPOS*64
  int pos = i >> 6, j = i & 63;
  float inv = exp2f(-(float)(2 * j) * (13.287712379549449f / 128.f));
  float a = (float)pos * inv;
  st[i] = sinf(a);
  ct[i] = cosf(a);
}

// scale folds the attention 1/sqrt(HD) into Q at RoPE time (1.0 for K).
__global__ void rope_apply(u16* __restrict__ T, const int* __restrict__ pid,
                           const float* __restrict__ st, const float* __restrict__ ct,
                           int nh, int total, float scale) {
  int i = blockIdx.x * 256 + threadIdx.x;
  if (i >= total) return;
  int j = i & 63;
  int rest = i >> 6;
  int h = rest % nh;
  int tok = rest / nh;
  int pos = pid[tok];
  long base = ((long)tok * nh + h) * 128;
  float c = ct[pos * 64 + j], s = st[pos * 64 + j];
  float a = bf2f(T[base + j]), b = bf2f(T[base + 64 + j]);
  T[base + j]      = f2bf((a * c - b * s) * scale);
  T[base + 64 + j] = f2bf((b * c + a * s) * scale);
}

// per-64-key-tile padding-mask flags: mf[b*(SS/64)+t] = any(amask<=0) in tile
__global__ void mask_flags(const float* __restrict__ amask, int* __restrict__ mf) {
  int i = threadIdx.x;                 // BB * SS/64 = 64 flags, one block
  if (i >= BB * (SS / 64)) return;
  int b = i / (SS / 64), tt = i % (SS / 64);
  int any = 0;
  for (int k = 0; k < 64; k++) any |= (amask[b * SS + tt * 64 + k] <= 0.f) ? 1 : 0;
  mf[i] = any;
}

// V [B,S,NKV,HD] -> Vt [B,NKV,HD,S]
__global__ __launch_bounds__(256) void vtrans(const u16* __restrict__ V, u16* __restrict__ Vt) {
  __shared__ u16 tile[64][68];
  const int s0 = blockIdx.x * 64, d0 = blockIdx.y * 64;
  const int bk = blockIdx.z;            // b*NKV + kvh
  const int b = bk >> 3, kvh = bk & 7;
  const int t = threadIdx.x;
  const int r = t >> 4, c4 = (t & 15) * 4;
#pragma unroll
  for (int i = 0; i < 4; i++) {
    int s = s0 + r + i * 16;
    ushort4 v = *(const ushort4*)&V[(((long)b * SS + s) * NKV + kvh) * HD + d0 + c4];
    tile[r + i * 16][c4 + 0] = v.x;
    tile[r + i * 16][c4 + 1] = v.y;
    tile[r + i * 16][c4 + 2] = v.z;
    tile[r + i * 16][c4 + 3] = v.w;
  }
  __syncthreads();
#pragma unroll
  for (int i = 0; i < 4; i++) {
    int d = r + i * 16;
    ushort4 o;
    o.x = tile[c4 + 0][d];
    o.y = tile[c4 + 1][d];
    o.z = tile[c4 + 2][d];
    o.w = tile[c4 + 3][d];
    *(ushort4*)&Vt[(((long)bk) * HD + d0 + d) * SS + s0 + c4] = o;
  }
}

// ---------------- GEMM: pipelined 256x256 tile, BK=32, 8 waves (2Mx4N) ----------
// (unchanged from round 9 — verified: total dropped 107us)

#define GEMM256_CORE(Aptr, Btptr, Kd)                                              \
  __shared__ __align__(16) u16 ring[65536]; /* 4 slots x (A 8K + B 8K u16) */      \
  const int tid = threadIdx.x;                                                     \
  const int lane = tid & 63;                                                       \
  const int wid = tid >> 6;                                                        \
  const int wm = wid >> 2, wn = wid & 3;                                           \
  const int fr = lane & 15, fq = lane >> 4;                                        \
  const int sr = tid >> 2;                               /* staging row 0..127 */  \
  const int ss = (tid & 3) ^ ((sr ^ (sr >> 2)) & 3);     /* pre-swizzled slot */   \
  const int csl = (fq ^ ((fr ^ (fr >> 2)) & 3)) << 4;    /* read col-slot byte */  \
  const u16* Ag0 = (Aptr) + (brow + sr) * (long)(Kd) + ss * 8;                     \
  const u16* Bg0 = (Btptr) + (bcol + sr) * (long)(Kd) + ss * 8;                    \
  f32x4 acc[8][4] = {};                                                            \
  auto stage = [&](int tt) {                                                       \
    u16* as_ = &ring[(tt & 3) * 16384];                                            \
    const u16* ag = Ag0 + (long)tt * 32;                                           \
    const u16* bg = Bg0 + (long)tt * 32;                                           \
    gload_lds16(ag, as_ + tid * 8);                                                \
    gload_lds16(ag + 128 * (long)(Kd), as_ + 4096 + tid * 8);                      \
    gload_lds16(bg, as_ + 8192 + tid * 8);                                         \
    gload_lds16(bg + 128 * (long)(Kd), as_ + 12288 + tid * 8);                     \
  };                                                                               \
  const int NT = (Kd) / 32;                                                        \
  stage(0); stage(1); stage(2);                                                    \
  _Pragma("unroll 1")                                                              \
  for (int t = 0; t < NT; ++t) {                                                   \
    if (t + 2 < NT)      asm volatile("s_waitcnt vmcnt(8)" ::: "memory");          \
    else if (t + 1 < NT) asm volatile("s_waitcnt vmcnt(4)" ::: "memory");          \
    else                 asm volatile("s_waitcnt vmcnt(0)" ::: "memory");          \
    __builtin_amdgcn_s_barrier();                                                  \
    __builtin_amdgcn_sched_barrier(0);                                             \
    if (t + 3 < NT) stage(t + 3);  /* slot (t-1)&3: readers done pre-barrier */    \
    const u16* as_ = &ring[(t & 3) * 16384];                                       \
    bf16x8 af[8], bfv[4];                                                          \
    _Pragma("unroll") for (int m = 0; m < 8; m++)                                  \
      af[m] = *(const bf16x8*)((const char*)as_ +                                  \
                               ((wm * 128 + m * 16 + fr) << 6) + csl);             \
    _Pragma("unroll") for (int n = 0; n < 4; n++)                                  \
      bfv[n] = *(const bf16x8*)((const char*)as_ + 16384 +                         \
                                ((wn * 64 + n * 16 + fr) << 6) + csl);             \
    asm volatile("s_waitcnt lgkmcnt(0)" ::: "memory");                             \
    __builtin_amdgcn_sched_barrier(0);                                             \
    __builtin_amdgcn_s_setprio(1);                                                 \
    _Pragma("unroll") for (int m = 0; m < 8; m++)                                  \
      _Pragma("unroll") for (int n = 0; n < 4; n++)                                \
        acc[m][n] = __builtin_amdgcn_mfma_f32_16x16x32_bf16(af[m], bfv[n],         \
                                                            acc[m][n], 0, 0, 0);   \
    __builtin_amdgcn_s_setprio(0);                                                 \
  }

// bijective XCD swizzle (nwg % 8 == 0 for both grids)
#define XCD_BLOCK_MAP()                                                            \
  const int nwg = gridDim.x * gridDim.y;                                           \
  int bid = blockIdx.y * gridDim.x + blockIdx.x;                                   \
  bid = (bid & 7) * (nwg >> 3) + (bid >> 3);                                       \
  const long brow = (long)(bid / gridDim.x) * 256;                                 \
  const long bcol = (long)(bid % gridDim.x) * 256;

// Fused QKV projection: Bt = [Wq^T | Wk^T | Wv^T] as [6144][4096].
__global__ __launch_bounds__(512) void gemm_qkv(const u16* __restrict__ A,
                                                const u16* __restrict__ Bt,
                                                u16* __restrict__ Qb,
                                                u16* __restrict__ Kb,
                                                u16* __restrict__ Vb) {
  XCD_BLOCK_MAP()
  GEMM256_CORE(A, Bt, HIDDEN)
  u16* dst;
  long nst, cb;
  if (bcol < 4096)      { dst = Qb; nst = 4096; cb = bcol; }
  else if (bcol < 5120) { dst = Kb; nst = 1024; cb = bcol - 4096; }
  else                  { dst = Vb; nst = 1024; cb = bcol - 5120; }
#pragma unroll
  for (int m = 0; m < 8; m++)
#pragma unroll
    for (int j = 0; j < 4; j++) {
      long row = brow + wm * 128 + m * 16 + fq * 4 + j;
#pragma unroll
      for (int n = 0; n < 4; n++)
        dst[row * nst + cb + wn * 64 + n * 16 + fr] = f2bf(acc[m][n][j]);
    }
}

// Output projection: C fp32 [M][HIDDEN]
__global__ __launch_bounds__(512) void gemm_out(const u16* __restrict__ A,
                                                const u16* __restrict__ Bt,
                                                float* __restrict__ C) {
  XCD_BLOCK_MAP()
  GEMM256_CORE(A, Bt, HIDDEN)
#pragma unroll
  for (int m = 0; m < 8; m++)
#pragma unroll
    for (int j = 0; j < 4; j++) {
      long row = brow + wm * 128 + m * 16 + fq * 4 + j;
#pragma unroll
      for (int n = 0; n < 4; n++)
        C[row * HIDDEN + bcol + wn * 64 + n * 16 + fr] = acc[m][n][j];
    }
}

// ---------------- flash attention (causal, GQA) ----------------
// Swapped QK^T (r8 math, verified correct) + gload_lds staging with
// pre-swizzled global source (linear LDS dest, rule #21) + double-buffered
// K/V (72KB, 2 blocks/CU) + T3 2-phase: ONE barrier/tile, stage(t+1) issued
// before compute(t) so HBM/L2 latency hides under MFMA+softmax. Mask-flag
// guard keeps pad-mask VALU out of the hot path. Softmax is lane-local:
// in-register tree + 2 shfl_xor (vs 32 ds_bpermute in the r6 layout).
// VGPR cliff at 128 (r5/r8 lessons): staging regs eliminated via gload_lds.

__global__ __launch_bounds__(256) void attn_fwd(const u16* __restrict__ Q,
                                                const u16* __restrict__ K,
                                                const u16* __restrict__ Vt,
                                                const float* __restrict__ amask,
                                                const int* __restrict__ mflag,
                                                u16* __restrict__ O) {
  const int b = blockIdx.z, h = blockIdx.y;
  const int qi = gridDim.x - 1 - blockIdx.x;   // heavy (high-qb) blocks first (LPT)
  const int qb = qi * 64;
  const int kvh = h >> 2;
  const int t = threadIdx.x, lane = t & 63, w = t >> 6;
  const int fr = lane & 15, fq = lane >> 4;

  __shared__ u16 Kl[2][64 * 128];     // [key][d] swizzled, 16KB per buf
  __shared__ u16 Vl[2][128 * 64];     // [d][key] swizzled, 16KB per buf
  __shared__ u16 PlA[4][16 * 64];     // per-wave [qrow][key], 8KB

  const int qrow = qb + w * 16 + fr;  // this lane's q row (B-operand + softmax)
  bf16x8 qf[4];
  {
    const long qbase = (((long)b * SS + qrow) * NH + h) * HD;
#pragma unroll
    for (int kk = 0; kk < 4; kk++)
      qf[kk] = *(const bf16x8*)&Q[qbase + kk * 32 + fq * 8];
  }

  const u16* Kh = K + (long)b * SS * NKV * HD + (long)kvh * HD;
  const u16* Vh = Vt + ((long)b * NKV + kvh) * (long)HD * SS;
  const float* Mh = amask + (long)b * SS;
  const int* Mf = mflag + b * (SS / 64);
  u16* Plw = PlA[w];

  // staging: linear LDS dest (i*2048 + t*8 elems), inverse-swizzled global src.
  // K tile [64][128]: byte o = i*4096 + t*16 -> row o>>8, colbyte (o&255)^((r&7)<<4)
  // V tile [128][64]: byte o -> row o>>7, colbyte (o&127)^((r&7)<<4)
  int koff[4], voff[4];
#pragma unroll
  for (int i = 0; i < 4; i++) {
    int o = i * 4096 + t * 16;
    int rk = o >> 8;
    int ck = (o & 255) ^ ((rk & 7) << 4);
    koff[i] = rk * (NKV * HD) + (ck >> 1);
    int rv = o >> 7;
    int cv = (o & 127) ^ ((rv & 7) << 4);
    voff[i] = rv * SS + (cv >> 1);
  }
  auto stage = [&](int kv0, int buf) {
    const u16* Kt = Kh + (long)kv0 * (NKV * HD);
    const u16* Vs = Vh + kv0;
#pragma unroll
    for (int i = 0; i < 4; i++)
      gload_lds16(Kt + koff[i], &Kl[buf][i * 2048 + t * 8]);
#pragma unroll
    for (int i = 0; i < 4; i++)
      gload_lds16(Vs + voff[i], &Vl[buf][i * 2048 + t * 8]);
  };

  f32x4 oacc[8] = {};
  float mrow = -1e30f, lrow = 0.f;
  const float L2E = 1.4426950408889634f;
  const int nt = qi + 1;

  stage(0, 0);

  for (int kvt = 0; kvt < nt; kvt++) {
    const int cur = kvt & 1;
    const int kv0 = kvt * 64;

    __syncthreads();               // auto vmcnt(0): stage(kvt->cur) complete;
                                   // readers of buf cur^1 (tile kvt-1) done.
    if (kvt + 1 < nt) stage(kv0 + 64, cur ^ 1);
    __builtin_amdgcn_sched_barrier(0);

    // ---- S^T = K Q^T (swapped operands; r8-verified) ----
    // sacc[n][j] = S[key = kv0 + n*16 + fq*4 + j][q = qrow]
    f32x4 sacc[4] = {};
    __builtin_amdgcn_s_setprio(1);
#pragma unroll
    for (int n = 0; n < 4; n++)
#pragma unroll
      for (int kk = 0; kk < 4; kk++) {
        bf16x8 kf = *(const bf16x8*)swzc(&Kl[cur][0], n * 16 + fr, kk * 32 + fq * 8, 128);
        sacc[n] = __builtin_amdgcn_mfma_f32_16x16x32_bf16(kf, qf[kk], sacc[n], 0, 0, 0);
      }
    __builtin_amdgcn_s_setprio(0);

    // ---- masking (wave-uniform guards; Q pre-scaled) ----
    if (kvt == qi) {                     // causal diagonal tile only
#pragma unroll
      for (int n = 0; n < 4; n++)
#pragma unroll
        for (int j = 0; j < 4; j++) {
          const int key = kv0 + n * 16 + fq * 4 + j;
          if (key > qrow) sacc[n][j] = -1e30f;
        }
    }
    if (Mf[kvt]) {                       // padding present in this tile (rare)
#pragma unroll
      for (int n = 0; n < 4; n++) {
        float4 mkv = *(const float4*)&Mh[kv0 + n * 16 + fq * 4];
#pragma unroll
        for (int j = 0; j < 4; j++)
          if ((&mkv.x)[j] <= 0.f) sacc[n][j] = -1e30f;
      }
    }

    // ---- online softmax: in-register tree + 2 shfl (defer-max T13) ----
    float mn[4];
#pragma unroll
    for (int n = 0; n < 4; n++)
      mn[n] = fmaxf(fmaxf(sacc[n][0], sacc[n][1]), fmaxf(sacc[n][2], sacc[n][3]));
    float mx = fmaxf(fmaxf(mn[0], mn[1]), fmaxf(mn[2], mn[3]));
    mx = fmaxf(mx, __shfl_xor(mx, 16, 64));
    mx = fmaxf(mx, __shfl_xor(mx, 32, 64));

    if (__any(mx > mrow + 8.f)) {
      float mnew = fmaxf(mrow, mx);
      float alpha = exp2f((mrow - mnew) * L2E);
      lrow *= alpha;
      mrow = mnew;
      float aj[4];
#pragma unroll
      for (int j = 0; j < 4; j++) aj[j] = __shfl(alpha, fq * 4 + j, 64);
#pragma unroll
      for (int no = 0; no < 8; no++)
#pragma unroll
        for (int j = 0; j < 4; j++) oacc[no][j] *= aj[j];
    }

    float sn[4];
#pragma unroll
    for (int n = 0; n < 4; n++) {
#pragma unroll
      for (int j = 0; j < 4; j++)
        sacc[n][j] = exp2f((sacc[n][j] - mrow) * L2E);
      sn[n] = (sacc[n][0] + sacc[n][1]) + (sacc[n][2] + sacc[n][3]);
    }
    float sum = (sn[0] + sn[1]) + (sn[2] + sn[3]);
    sum += __shfl_xor(sum, 16, 64);
    sum += __shfl_xor(sum, 32, 64);
    lrow += sum;

    // ---- P -> LDS: row = fr (q-local), cols n*16+fq*4..+3 (ds_write_b64) ----
#pragma unroll
    for (int n = 0; n < 4; n++) {
      ushort4 pw;
      pw.x = f2bf(sacc[n][0]);
      pw.y = f2bf(sacc[n][1]);
      pw.z = f2bf(sacc[n][2]);
      pw.w = f2bf(sacc[n][3]);
      *(ushort4*)swzp(Plw, fr, n * 16 + fq * 4, 64) = pw;
    }

    // ---- O += P V ----
    __builtin_amdgcn_s_setprio(1);
#pragma unroll
    for (int kk = 0; kk < 2; kk++) {
      bf16x8 pf = *(const bf16x8*)swzc(Plw, fr, kk * 32 + fq * 8, 64);
#pragma unroll
      for (int no = 0; no < 8; no++) {
        bf16x8 vf = *(const bf16x8*)swzc(&Vl[cur][0], no * 16 + fr, kk * 32 + fq * 8, 64);
        oacc[no] = __builtin_amdgcn_mfma_f32_16x16x32_bf16(pf, vf, oacc[no], 0, 0, 0);
      }
    }
    __builtin_amdgcn_s_setprio(0);
  }

  // ---- epilogue: fetch lrow for O's q rows (q = qb + w*16 + fq*4 + j) ----
  float lj[4];
#pragma unroll
  for (int j = 0; j < 4; j++) lj[j] = __shfl(lrow, fq * 4 + j, 64);
#pragma unroll
  for (int j = 0; j < 4; j++) {
    const int row = qb + w * 16 + fq * 4 + j;
    const float inv = 1.0f / lj[j];
    const long obase = (((long)b * SS + row) * NH + h) * HD;
#pragma unroll
    for (int no = 0; no < 8; no++)
      O[obase + no * 16 + fr] = f2bf(oacc[no][j] * inv);
  }
}

// ---------------- launch ----------------

extern "C" void kernel_launch(void* const* d_in, const int* in_sizes, int n_in,
                              void* d_out, int out_size, void* d_ws, size_t ws_size,
                              hipStream_t stream) {
  const float* hs    = (const float*)d_in[0];
  const float* amask = (const float*)d_in[1];
  const int*   pid   = (const int*)d_in[2];
  const float* Wq    = (const float*)d_in[3];
  const float* Wk    = (const float*)d_in[4];
  const float* Wv    = (const float*)d_in[5];
  const float* Wo    = (const float*)d_in[6];
  float* out = (float*)d_out;

  char* ws = (char*)d_ws;
  const size_t MB = 1024ull * 1024ull;
  u16* Xb    = (u16*)(ws + 0);         // 32MB, later reused as attention output
  u16* Wqkvt = (u16*)(ws + 32 * MB);   // 48MB: [Wq^T|Wk^T|Wv^T] as [6144][4096]
  u16* Wot   = (u16*)(ws + 80 * MB);   // 32MB
  u16* Qb    = (u16*)(ws + 112 * MB);  // 32MB
  u16* Kb    = (u16*)(ws + 144 * MB);  // 8MB
  u16* Vb    = (u16*)(ws + 152 * MB);  // 8MB
  u16* Vtb   = (u16*)(ws + 160 * MB);  // 8MB
  float* st  = (float*)(ws + 168 * MB);// 1MB
  float* ct  = (float*)(ws + 169 * MB);// 1MB
  int* mf    = (int*)(ws + 170 * MB);  // 256B
  u16* Ab = Xb;                        // alias: Xb dead after QKV GEMM

  rope_table<<<(MAXPOS * 64) / 256, 256, 0, stream>>>(st, ct);
  mask_flags<<<1, 64, 0, stream>>>(amask, mf);
  conv_bf16<<<(TOK * HIDDEN / 8) / 256, 256, 0, stream>>>(hs, Xb, TOK * HIDDEN / 8);
  conv_transpose<<<dim3(HIDDEN / 64, HIDDEN / 64), 256, 0, stream>>>(Wq, Wqkvt, HIDDEN, HIDDEN);
  conv_transpose<<<dim3(1024 / 64, HIDDEN / 64), 256, 0, stream>>>(Wk, Wqkvt + 4096ull * 4096, HIDDEN, 1024);
  conv_transpose<<<dim3(1024 / 64, HIDDEN / 64), 256, 0, stream>>>(Wv, Wqkvt + 5120ull * 4096, HIDDEN, 1024);
  conv_transpose<<<dim3(HIDDEN / 64, HIDDEN / 64), 256, 0, stream>>>(Wo, Wot, HIDDEN, HIDDEN);

  gemm_qkv<<<dim3(NQKV / 256, TOK / 256), 512, 0, stream>>>(Xb, Wqkvt, Qb, Kb, Vb);

  const float qscale = 0.08838834764831845f;  // 1/sqrt(HD)
  rope_apply<<<(TOK * NH * 64) / 256, 256, 0, stream>>>(Qb, pid, st, ct, NH, TOK * NH * 64, qscale);
  rope_apply<<<(TOK * NKV * 64) / 256, 256, 0, stream>>>(Kb, pid, st, ct, NKV, TOK * NKV * 64, 1.0f);

  vtrans<<<dim3(SS / 64, HD / 64, BB * NKV), 256, 0, stream>>>(Vb, Vtb);

  attn_fwd<<<dim3(SS / 64, NH, BB), 256, 0, stream>>>(Qb, Kb, Vtb, amask, mf, Ab);

  gemm_out<<<dim3(HIDDEN / 256, TOK / 256), 512, 0, stream>>>(Ab, Wot, out);
}

// Round 16
// 719.548 us; speedup vs baseline: 1.0409x; 1.0409x over previous
//
#include <hip/hip_runtime.h>
#include <hip/hip_bf16.h>

typedef unsigned short u16;
typedef __attribute__((ext_vector_type(8))) short bf16x8;   // MFMA A/B operand (8 bf16 = 4 VGPR)
typedef __attribute__((ext_vector_type(8))) unsigned short u16x8;
typedef __attribute__((ext_vector_type(4))) float f32x4;    // MFMA C/D operand

#define HIDDEN 4096
#define NH 32
#define NKV 8
#define HD 128
#define BB 2
#define SS 2048
#define TOK (BB * SS)   // 4096
#define MAXPOS 4096
#define NQKV 6144        // 4096 + 1024 + 1024

// Native HW conversion (RNE on gfx950); adjacent pairs fuse to v_cvt_pk_bf16_f32.
__device__ __forceinline__ u16 f2bf(float f) {
  __hip_bfloat16 h = __float2bfloat16(f);
  union { __hip_bfloat16 h; u16 u; } cv;
  cv.h = h;
  return cv.u;
}
__device__ __forceinline__ float bf2f(u16 u) {
  return __uint_as_float(((unsigned)u) << 16);
}

__device__ __forceinline__ void gload_lds16(const u16* g, u16* l) {
  __builtin_amdgcn_global_load_lds(
      (const __attribute__((address_space(1))) unsigned int*)g,
      (__attribute__((address_space(3))) unsigned int*)l, 16, 0, 0);
}

// XOR-swizzled LDS addressing (T2): same involution on write and read.
__device__ __forceinline__ u16* swzp(u16* base, int row, int col, int stride) {
  int off = (row * stride + col) * 2;
  off ^= (row & 7) << 4;
  return (u16*)((char*)base + off);
}
__device__ __forceinline__ const u16* swzc(const u16* base, int row, int col, int stride) {
  int off = (row * stride + col) * 2;
  off ^= (row & 7) << 4;
  return (const u16*)((const char*)base + off);
}

// ---------------- conversion kernels ----------------

__global__ void conv_bf16(const float* __restrict__ X, u16* __restrict__ Y, int n8) {
  int i = blockIdx.x * 256 + threadIdx.x;
  if (i >= n8) return;
  const float4* p = (const float4*)X;
  float4 a = p[2 * (long)i], b = p[2 * (long)i + 1];
  u16x8 o;
  o[0] = f2bf(a.x); o[1] = f2bf(a.y); o[2] = f2bf(a.z); o[3] = f2bf(a.w);
  o[4] = f2bf(b.x); o[5] = f2bf(b.y); o[6] = f2bf(b.z); o[7] = f2bf(b.w);
  *(u16x8*)&Y[(long)i * 8] = o;
}

// W [K][N] fp32  ->  Wt [N][K] bf16
__global__ __launch_bounds__(256) void conv_transpose(const float* __restrict__ W,
                                                      u16* __restrict__ Wt,
                                                      int K, int N) {
  __shared__ float tile[64][65];
  const int n0 = blockIdx.x * 64, k0 = blockIdx.y * 64;
  const int t = threadIdx.x;
  const int r = t >> 4, c4 = (t & 15) * 4;
#pragma unroll
  for (int i = 0; i < 4; i++) {
    float4 v = *(const float4*)&W[(long)(k0 + r + i * 16) * N + n0 + c4];
    tile[r + i * 16][c4 + 0] = v.x;
    tile[r + i * 16][c4 + 1] = v.y;
    tile[r + i * 16][c4 + 2] = v.z;
    tile[r + i * 16][c4 + 3] = v.w;
  }
  __syncthreads();
#pragma unroll
  for (int i = 0; i < 4; i++) {
    int n = r + i * 16;
    ushort4 o;
    o.x = f2bf(tile[c4 + 0][n]);
    o.y = f2bf(tile[c4 + 1][n]);
    o.z = f2bf(tile[c4 + 2][n]);
    o.w = f2bf(tile[c4 + 3][n]);
    *(ushort4*)&Wt[(long)(n0 + n) * K + k0 + c4] = o;
  }
}

// ---------------- RoPE ----------------

__global__ void rope_table(float* __restrict__ st, float* __restrict__ ct) {
  int i = blockIdx.x * 256 + threadIdx.x;   // MAXPOS*64
  int pos = i >> 6, j = i & 63;
  float inv = exp2f(-(float)(2 * j) * (13.287712379549449f / 128.f));
  float a = (float)pos * inv;
  st[i] = sinf(a);
  ct[i] = cosf(a);
}

// scale folds the attention 1/sqrt(HD) into Q at RoPE time (1.0 for K).
// Vectorized x4: each thread handles 4 rotation pairs (8B loads/stores).
__global__ void rope_apply(u16* __restrict__ T, const int* __restrict__ pid,
                           const float* __restrict__ st, const float* __restrict__ ct,
                           int nh, int total4, float scale) {
  int i = blockIdx.x * 256 + threadIdx.x;   // total4 = TOK*nh*16
  if (i >= total4) return;
  int j4 = (i & 15) * 4;
  int rest = i >> 4;
  int h = rest % nh;
  int tok = rest / nh;
  int pos = pid[tok];
  long base = ((long)tok * nh + h) * 128;
  float4 c = *(const float4*)&ct[pos * 64 + j4];
  float4 s = *(const float4*)&st[pos * 64 + j4];
  ushort4 a4 = *(const ushort4*)&T[base + j4];
  ushort4 b4 = *(const ushort4*)&T[base + 64 + j4];
  ushort4 ra, rb;
  {
    float a = bf2f(a4.x), b = bf2f(b4.x);
    ra.x = f2bf((a * c.x - b * s.x) * scale);
    rb.x = f2bf((b * c.x + a * s.x) * scale);
  }
  {
    float a = bf2f(a4.y), b = bf2f(b4.y);
    ra.y = f2bf((a * c.y - b * s.y) * scale);
    rb.y = f2bf((b * c.y + a * s.y) * scale);
  }
  {
    float a = bf2f(a4.z), b = bf2f(b4.z);
    ra.z = f2bf((a * c.z - b * s.z) * scale);
    rb.z = f2bf((b * c.z + a * s.z) * scale);
  }
  {
    float a = bf2f(a4.w), b = bf2f(b4.w);
    ra.w = f2bf((a * c.w - b * s.w) * scale);
    rb.w = f2bf((b * c.w + a * s.w) * scale);
  }
  *(ushort4*)&T[base + j4] = ra;
  *(ushort4*)&T[base + 64 + j4] = rb;
}

// per-64-key-tile padding-mask flags: mf[b*(SS/64)+t] = any(amask<=0) in tile
__global__ void mask_flags(const float* __restrict__ amask, int* __restrict__ mf) {
  int i = threadIdx.x;                 // BB * SS/64 = 64 flags, one block
  if (i >= BB * (SS / 64)) return;
  int b = i / (SS / 64), tt = i % (SS / 64);
  int any = 0;
  for (int k = 0; k < 64; k++) any |= (amask[b * SS + tt * 64 + k] <= 0.f) ? 1 : 0;
  mf[i] = any;
}

// V [B,S,NKV,HD] -> Vt [B,NKV,HD,S]
__global__ __launch_bounds__(256) void vtrans(const u16* __restrict__ V, u16* __restrict__ Vt) {
  __shared__ u16 tile[64][68];
  const int s0 = blockIdx.x * 64, d0 = blockIdx.y * 64;
  const int bk = blockIdx.z;            // b*NKV + kvh
  const int b = bk >> 3, kvh = bk & 7;
  const int t = threadIdx.x;
  const int r = t >> 4, c4 = (t & 15) * 4;
#pragma unroll
  for (int i = 0; i < 4; i++) {
    int s = s0 + r + i * 16;
    ushort4 v = *(const ushort4*)&V[(((long)b * SS + s) * NKV + kvh) * HD + d0 + c4];
    tile[r + i * 16][c4 + 0] = v.x;
    tile[r + i * 16][c4 + 1] = v.y;
    tile[r + i * 16][c4 + 2] = v.z;
    tile[r + i * 16][c4 + 3] = v.w;
  }
  __syncthreads();
#pragma unroll
  for (int i = 0; i < 4; i++) {
    int d = r + i * 16;
    ushort4 o;
    o.x = tile[c4 + 0][d];
    o.y = tile[c4 + 1][d];
    o.z = tile[c4 + 2][d];
    o.w = tile[c4 + 3][d];
    *(ushort4*)&Vt[(((long)bk) * HD + d0 + d) * SS + s0 + c4] = o;
  }
}

// ---------------- GEMM: pipelined 256x256 tile, BK=32, 8 waves (2Mx4N) ----------
// r9 structure + r16 change: the forced lgkmcnt(0) drain before the MFMA
// cluster is REMOVED — the ds_reads are compiler-visible loads, so hipcc
// emits fine-grained per-fragment lgkmcnt(N) and overlaps ds_read latency
// under the first MFMAs (guide §5/m97 asm). Counted vmcnt + single raw
// barrier per K-step unchanged (proven r9: −107us).

#define GEMM256_CORE(Aptr, Btptr, Kd)                                              \
  __shared__ __align__(16) u16 ring[65536]; /* 4 slots x (A 8K + B 8K u16) */      \
  const int tid = threadIdx.x;                                                     \
  const int lane = tid & 63;                                                       \
  const int wid = tid >> 6;                                                        \
  const int wm = wid >> 2, wn = wid & 3;                                           \
  const int fr = lane & 15, fq = lane >> 4;                                        \
  const int sr = tid >> 2;                               /* staging row 0..127 */  \
  const int ss = (tid & 3) ^ ((sr ^ (sr >> 2)) & 3);     /* pre-swizzled slot */   \
  const int csl = (fq ^ ((fr ^ (fr >> 2)) & 3)) << 4;    /* read col-slot byte */  \
  const u16* Ag0 = (Aptr) + (brow + sr) * (long)(Kd) + ss * 8;                     \
  const u16* Bg0 = (Btptr) + (bcol + sr) * (long)(Kd) + ss * 8;                    \
  f32x4 acc[8][4] = {};                                                            \
  auto stage = [&](int tt) {                                                       \
    u16* as_ = &ring[(tt & 3) * 16384];                                            \
    const u16* ag = Ag0 + (long)tt * 32;                                           \
    const u16* bg = Bg0 + (long)tt * 32;                                           \
    gload_lds16(ag, as_ + tid * 8);                                                \
    gload_lds16(ag + 128 * (long)(Kd), as_ + 4096 + tid * 8);                      \
    gload_lds16(bg, as_ + 8192 + tid * 8);                                         \
    gload_lds16(bg + 128 * (long)(Kd), as_ + 12288 + tid * 8);                     \
  };                                                                               \
  const int NT = (Kd) / 32;                                                        \
  stage(0); stage(1); stage(2);                                                    \
  _Pragma("unroll 1")                                                              \
  for (int t = 0; t < NT; ++t) {                                                   \
    if (t + 2 < NT)      asm volatile("s_waitcnt vmcnt(8)" ::: "memory");          \
    else if (t + 1 < NT) asm volatile("s_waitcnt vmcnt(4)" ::: "memory");          \
    else                 asm volatile("s_waitcnt vmcnt(0)" ::: "memory");          \
    __builtin_amdgcn_s_barrier();                                                  \
    __builtin_amdgcn_sched_barrier(0);                                             \
    if (t + 3 < NT) stage(t + 3);  /* slot (t-1)&3: readers done pre-barrier */    \
    const u16* as_ = &ring[(t & 3) * 16384];                                       \
    bf16x8 af[8], bfv[4];                                                          \
    _Pragma("unroll") for (int m = 0; m < 8; m++)                                  \
      af[m] = *(const bf16x8*)((const char*)as_ +                                  \
                               ((wm * 128 + m * 16 + fr) << 6) + csl);             \
    _Pragma("unroll") for (int n = 0; n < 4; n++)                                  \
      bfv[n] = *(const bf16x8*)((const char*)as_ + 16384 +                         \
                                ((wn * 64 + n * 16 + fr) << 6) + csl);             \
    __builtin_amdgcn_s_setprio(1);                                                 \
    _Pragma("unroll") for (int m = 0; m < 8; m++)                                  \
      _Pragma("unroll") for (int n = 0; n < 4; n++)                                \
        acc[m][n] = __builtin_amdgcn_mfma_f32_16x16x32_bf16(af[m], bfv[n],         \
                                                            acc[m][n], 0, 0, 0);   \
    __builtin_amdgcn_s_setprio(0);                                                 \
  }

// bijective XCD swizzle (nwg % 8 == 0 for both grids)
#define XCD_BLOCK_MAP()                                                            \
  const int nwg = gridDim.x * gridDim.y;                                           \
  int bid = blockIdx.y * gridDim.x + blockIdx.x;                                   \
  bid = (bid & 7) * (nwg >> 3) + (bid >> 3);                                       \
  const long brow = (long)(bid / gridDim.x) * 256;                                 \
  const long bcol = (long)(bid % gridDim.x) * 256;

// Fused QKV projection: Bt = [Wq^T | Wk^T | Wv^T] as [6144][4096].
__global__ __launch_bounds__(512) void gemm_qkv(const u16* __restrict__ A,
                                                const u16* __restrict__ Bt,
                                                u16* __restrict__ Qb,
                                                u16* __restrict__ Kb,
                                                u16* __restrict__ Vb) {
  XCD_BLOCK_MAP()
  GEMM256_CORE(A, Bt, HIDDEN)
  u16* dst;
  long nst, cb;
  if (bcol < 4096)      { dst = Qb; nst = 4096; cb = bcol; }
  else if (bcol < 5120) { dst = Kb; nst = 1024; cb = bcol - 4096; }
  else                  { dst = Vb; nst = 1024; cb = bcol - 5120; }
#pragma unroll
  for (int m = 0; m < 8; m++)
#pragma unroll
    for (int j = 0; j < 4; j++) {
      long row = brow + wm * 128 + m * 16 + fq * 4 + j;
#pragma unroll
      for (int n = 0; n < 4; n++)
        dst[row * nst + cb + wn * 64 + n * 16 + fr] = f2bf(acc[m][n][j]);
    }
}

// Output projection: C fp32 [M][HIDDEN]
__global__ __launch_bounds__(512) void gemm_out(const u16* __restrict__ A,
                                                const u16* __restrict__ Bt,
                                                float* __restrict__ C) {
  XCD_BLOCK_MAP()
  GEMM256_CORE(A, Bt, HIDDEN)
#pragma unroll
  for (int m = 0; m < 8; m++)
#pragma unroll
    for (int j = 0; j < 4; j++) {
      long row = brow + wm * 128 + m * 16 + fq * 4 + j;
#pragma unroll
      for (int n = 0; n < 4; n++)
        C[row * HIDDEN + bcol + wn * 64 + n * 16 + fr] = acc[m][n][j];
    }
}

// ---------------- flash attention (causal, GQA) ----------------
// r10 structure (verified 311us): swapped QK^T + gload_lds staging with
// pre-swizzled global source + double-buffered K/V (72KB, 2 blocks/CU) +
// ONE barrier/tile with stage(t+1) issued before compute(t). Lane-local
// softmax (2 shfl_xor). VGPR 96 — keep <= 128 (r5/r8 cliff).
// r16 change: f2bf now lowers to HW cvt (pairs fuse to v_cvt_pk_bf16_f32).

__global__ __launch_bounds__(256) void attn_fwd(const u16* __restrict__ Q,
                                                const u16* __restrict__ K,
                                                const u16* __restrict__ Vt,
                                                const float* __restrict__ amask,
                                                const int* __restrict__ mflag,
                                                u16* __restrict__ O) {
  const int b = blockIdx.z, h = blockIdx.y;
  const int qi = gridDim.x - 1 - blockIdx.x;   // heavy (high-qb) blocks first (LPT)
  const int qb = qi * 64;
  const int kvh = h >> 2;
  const int t = threadIdx.x, lane = t & 63, w = t >> 6;
  const int fr = lane & 15, fq = lane >> 4;

  __shared__ u16 Kl[2][64 * 128];     // [key][d] swizzled, 16KB per buf
  __shared__ u16 Vl[2][128 * 64];     // [d][key] swizzled, 16KB per buf
  __shared__ u16 PlA[4][16 * 64];     // per-wave [qrow][key], 8KB

  const int qrow = qb + w * 16 + fr;  // this lane's q row (B-operand + softmax)
  bf16x8 qf[4];
  {
    const long qbase = (((long)b * SS + qrow) * NH + h) * HD;
#pragma unroll
    for (int kk = 0; kk < 4; kk++)
      qf[kk] = *(const bf16x8*)&Q[qbase + kk * 32 + fq * 8];
  }

  const u16* Kh = K + (long)b * SS * NKV * HD + (long)kvh * HD;
  const u16* Vh = Vt + ((long)b * NKV + kvh) * (long)HD * SS;
  const float* Mh = amask + (long)b * SS;
  const int* Mf = mflag + b * (SS / 64);
  u16* Plw = PlA[w];

  // staging: linear LDS dest (i*2048 + t*8 elems), inverse-swizzled global src.
  int koff[4], voff[4];
#pragma unroll
  for (int i = 0; i < 4; i++) {
    int o = i * 4096 + t * 16;
    int rk = o >> 8;
    int ck = (o & 255) ^ ((rk & 7) << 4);
    koff[i] = rk * (NKV * HD) + (ck >> 1);
    int rv = o >> 7;
    int cv = (o & 127) ^ ((rv & 7) << 4);
    voff[i] = rv * SS + (cv >> 1);
  }
  auto stage = [&](int kv0, int buf) {
    const u16* Kt = Kh + (long)kv0 * (NKV * HD);
    const u16* Vs = Vh + kv0;
#pragma unroll
    for (int i = 0; i < 4; i++)
      gload_lds16(Kt + koff[i], &Kl[buf][i * 2048 + t * 8]);
#pragma unroll
    for (int i = 0; i < 4; i++)
      gload_lds16(Vs + voff[i], &Vl[buf][i * 2048 + t * 8]);
  };

  f32x4 oacc[8] = {};
  float mrow = -1e30f, lrow = 0.f;
  const float L2E = 1.4426950408889634f;
  const int nt = qi + 1;

  stage(0, 0);

  for (int kvt = 0; kvt < nt; kvt++) {
    const int cur = kvt & 1;
    const int kv0 = kvt * 64;

    __syncthreads();               // auto vmcnt(0): stage(kvt->cur) complete;
                                   // readers of buf cur^1 (tile kvt-1) done.
    if (kvt + 1 < nt) stage(kv0 + 64, cur ^ 1);
    __builtin_amdgcn_sched_barrier(0);

    // ---- S^T = K Q^T (swapped operands) ----
    // sacc[n][j] = S[key = kv0 + n*16 + fq*4 + j][q = qrow]
    f32x4 sacc[4] = {};
    __builtin_amdgcn_s_setprio(1);
#pragma unroll
    for (int n = 0; n < 4; n++)
#pragma unroll
      for (int kk = 0; kk < 4; kk++) {
        bf16x8 kf = *(const bf16x8*)swzc(&Kl[cur][0], n * 16 + fr, kk * 32 + fq * 8, 128);
        sacc[n] = __builtin_amdgcn_mfma_f32_16x16x32_bf16(kf, qf[kk], sacc[n], 0, 0, 0);
      }
    __builtin_amdgcn_s_setprio(0);

    // ---- masking (wave-uniform guards; Q pre-scaled) ----
    if (kvt == qi) {                     // causal diagonal tile only
#pragma unroll
      for (int n = 0; n < 4; n++)
#pragma unroll
        for (int j = 0; j < 4; j++) {
          const int key = kv0 + n * 16 + fq * 4 + j;
          if (key > qrow) sacc[n][j] = -1e30f;
        }
    }
    if (Mf[kvt]) {                       // padding present in this tile (rare)
#pragma unroll
      for (int n = 0; n < 4; n++) {
        float4 mkv = *(const float4*)&Mh[kv0 + n * 16 + fq * 4];
#pragma unroll
        for (int j = 0; j < 4; j++)
          if ((&mkv.x)[j] <= 0.f) sacc[n][j] = -1e30f;
      }
    }

    // ---- online softmax: in-register tree + 2 shfl (defer-max T13) ----
    float mn[4];
#pragma unroll
    for (int n = 0; n < 4; n++)
      mn[n] = fmaxf(fmaxf(sacc[n][0], sacc[n][1]), fmaxf(sacc[n][2], sacc[n][3]));
    float mx = fmaxf(fmaxf(mn[0], mn[1]), fmaxf(mn[2], mn[3]));
    mx = fmaxf(mx, __shfl_xor(mx, 16, 64));
    mx = fmaxf(mx, __shfl_xor(mx, 32, 64));

    if (__any(mx > mrow + 8.f)) {
      float mnew = fmaxf(mrow, mx);
      float alpha = exp2f((mrow - mnew) * L2E);
      lrow *= alpha;
      mrow = mnew;
      float aj[4];
#pragma unroll
      for (int j = 0; j < 4; j++) aj[j] = __shfl(alpha, fq * 4 + j, 64);
#pragma unroll
      for (int no = 0; no < 8; no++)
#pragma unroll
        for (int j = 0; j < 4; j++) oacc[no][j] *= aj[j];
    }

    float sn[4];
#pragma unroll
    for (int n = 0; n < 4; n++) {
#pragma unroll
      for (int j = 0; j < 4; j++)
        sacc[n][j] = exp2f((sacc[n][j] - mrow) * L2E);
      sn[n] = (sacc[n][0] + sacc[n][1]) + (sacc[n][2] + sacc[n][3]);
    }
    float sum = (sn[0] + sn[1]) + (sn[2] + sn[3]);
    sum += __shfl_xor(sum, 16, 64);
    sum += __shfl_xor(sum, 32, 64);
    lrow += sum;

    // ---- P -> LDS: row = fr (q-local), cols n*16+fq*4..+3 (ds_write_b64) ----
#pragma unroll
    for (int n = 0; n < 4; n++) {
      ushort4 pw;
      pw.x = f2bf(sacc[n][0]);
      pw.y = f2bf(sacc[n][1]);
      pw.z = f2bf(sacc[n][2]);
      pw.w = f2bf(sacc[n][3]);
      *(ushort4*)swzp(Plw, fr, n * 16 + fq * 4, 64) = pw;
    }

    // ---- O += P V ----
    __builtin_amdgcn_s_setprio(1);
#pragma unroll
    for (int kk = 0; kk < 2; kk++) {
      bf16x8 pf = *(const bf16x8*)swzc(Plw, fr, kk * 32 + fq * 8, 64);
#pragma unroll
      for (int no = 0; no < 8; no++) {
        bf16x8 vf = *(const bf16x8*)swzc(&Vl[cur][0], no * 16 + fr, kk * 32 + fq * 8, 64);
        oacc[no] = __builtin_amdgcn_mfma_f32_16x16x32_bf16(pf, vf, oacc[no], 0, 0, 0);
      }
    }
    __builtin_amdgcn_s_setprio(0);
  }

  // ---- epilogue: fetch lrow for O's q rows (q = qb + w*16 + fq*4 + j) ----
  float lj[4];
#pragma unroll
  for (int j = 0; j < 4; j++) lj[j] = __shfl(lrow, fq * 4 + j, 64);
#pragma unroll
  for (int j = 0; j < 4; j++) {
    const int row = qb + w * 16 + fq * 4 + j;
    const float inv = 1.0f / lj[j];
    const long obase = (((long)b * SS + row) * NH + h) * HD;
#pragma unroll
    for (int no = 0; no < 8; no++)
      O[obase + no * 16 + fr] = f2bf(oacc[no][j] * inv);
  }
}

// ---------------- launch ----------------

extern "C" void kernel_launch(void* const* d_in, const int* in_sizes, int n_in,
                              void* d_out, int out_size, void* d_ws, size_t ws_size,
                              hipStream_t stream) {
  const float* hs    = (const float*)d_in[0];
  const float* amask = (const float*)d_in[1];
  const int*   pid   = (const int*)d_in[2];
  const float* Wq    = (const float*)d_in[3];
  const float* Wk    = (const float*)d_in[4];
  const float* Wv    = (const float*)d_in[5];
  const float* Wo    = (const float*)d_in[6];
  float* out = (float*)d_out;

  char* ws = (char*)d_ws;
  const size_t MB = 1024ull * 1024ull;
  u16* Xb    = (u16*)(ws + 0);         // 32MB, later reused as attention output
  u16* Wqkvt = (u16*)(ws + 32 * MB);   // 48MB: [Wq^T|Wk^T|Wv^T] as [6144][4096]
  u16* Wot   = (u16*)(ws + 80 * MB);   // 32MB
  u16* Qb    = (u16*)(ws + 112 * MB);  // 32MB
  u16* Kb    = (u16*)(ws + 144 * MB);  // 8MB
  u16* Vb    = (u16*)(ws + 152 * MB);  // 8MB
  u16* Vtb   = (u16*)(ws + 160 * MB);  // 8MB
  float* st  = (float*)(ws + 168 * MB);// 1MB
  float* ct  = (float*)(ws + 169 * MB);// 1MB
  int* mf    = (int*)(ws + 170 * MB);  // 256B
  u16* Ab = Xb;                        // alias: Xb dead after QKV GEMM

  rope_table<<<(MAXPOS * 64) / 256, 256, 0, stream>>>(st, ct);
  mask_flags<<<1, 64, 0, stream>>>(amask, mf);
  conv_bf16<<<(TOK * HIDDEN / 8) / 256, 256, 0, stream>>>(hs, Xb, TOK * HIDDEN / 8);
  conv_transpose<<<dim3(HIDDEN / 64, HIDDEN / 64), 256, 0, stream>>>(Wq, Wqkvt, HIDDEN, HIDDEN);
  conv_transpose<<<dim3(1024 / 64, HIDDEN / 64), 256, 0, stream>>>(Wk, Wqkvt + 4096ull * 4096, HIDDEN, 1024);
  conv_transpose<<<dim3(1024 / 64, HIDDEN / 64), 256, 0, stream>>>(Wv, Wqkvt + 5120ull * 4096, HIDDEN, 1024);
  conv_transpose<<<dim3(HIDDEN / 64, HIDDEN / 64), 256, 0, stream>>>(Wo, Wot, HIDDEN, HIDDEN);

  gemm_qkv<<<dim3(NQKV / 256, TOK / 256), 512, 0, stream>>>(Xb, Wqkvt, Qb, Kb, Vb);

  const float qscale = 0.08838834764831845f;  // 1/sqrt(HD)
  rope_apply<<<(TOK * NH * 16) / 256, 256, 0, stream>>>(Qb, pid, st, ct, NH, TOK * NH * 16, qscale);
  rope_apply<<<(TOK * NKV * 16) / 256, 256, 0, stream>>>(Kb, pid, st, ct, NKV, TOK * NKV * 16, 1.0f);

  vtrans<<<dim3(SS / 64, HD / 64, BB * NKV), 256, 0, stream>>>(Vb, Vtb);

  attn_fwd<<<dim3(SS / 64, NH, BB), 256, 0, stream>>>(Qb, Kb, Vtb, amask, mf, Ab);

  gemm_out<<<dim3(HIDDEN / 256, TOK / 256), 512, 0, stream>>>(Ab, Wot, out);
}